// Round 3
// baseline (1437.868 us; speedup 1.0000x reference)
//
#include <hip/hip_runtime.h>
#include <math.h>

typedef unsigned short U16;
typedef unsigned int   U32;
typedef __attribute__((ext_vector_type(8))) __bf16 bf16x8;
typedef __attribute__((ext_vector_type(4))) float  f32x4;

__device__ __forceinline__ U16 f2bf(float f) {
    __bf16 h = (__bf16)f;
    return __builtin_bit_cast(U16, h);
}
__device__ __forceinline__ float gelu_f(float y) {
    return 0.5f * y * (1.0f + erff(y * 0.70710678118654752f));
}

#define XT_S  69     // fp32 x-tile row stride (68 cols + 1 pad)
#define XT_CS 207    // 3 * XT_S, per-channel stride
#define ELS   40     // El per-pixel channel stride (32 ch + 8 pad) -> 80 B, 16B-aligned
#define WBS   68     // epilogue restage row stride (even mult of 4 -> 16B-aligned float4)

// ---------------- K0: one-time weight fp32 -> bf16 conversion ----------------
__global__ void k0_cvt(const float* __restrict__ wB, const float* __restrict__ wf,
                       U16* __restrict__ wBb, U16* __restrict__ wfb)
{
    const int i = blockIdx.x * 256 + threadIdx.x;   // 1024 blocks -> 262144 = both sizes
    wBb[i] = f2bf(wB[i]);
    wfb[i] = f2bf(wf[i]);
}

// ---------------- K1: edge maps + 4 branch GEMMs + BN + GELU + pooled ----------------
// ef layout [b][c][pix]. ef preferentially lives in d_ws (cached coarse-grained);
// falls back to d_out. Epilogue: LDS restage -> float4 (dwordx4) stores: 4x fewer
// store instructions (latency-bound store path on d_out-class memory).
__global__ __launch_bounds__(256, 2)
void k1_branch(const float* __restrict__ x, const U16* __restrict__ wBb,
               const float* __restrict__ bB, const float* __restrict__ bg,
               const float* __restrict__ bbt, float* __restrict__ ef,
               float* __restrict__ pooled)
{
    __shared__ __align__(16) char smem[46976];
    float* xs  = (float*)smem;                 // 32*207 fp32 = 26496 B
    U16*   El  = (U16*)(smem + 26496);         // 4*64*40 U16 = 20480 B
    float* stg = (float*)(smem + 26496);       // epilogue: aliases El (dead after k-loop)

    const int tid  = threadIdx.x;
    // bijective chunked XCD swizzle: dispatch p -> XCD p%8; each XCD gets a
    // contiguous 128-block chunk so h-adjacent blocks share an L2 (halo reuse).
    const int bi   = ((blockIdx.x & 7) << 7) | (blockIdx.x >> 3);
    const int b    = bi >> 8;
    const int rem  = bi & 255;
    const int h    = rem >> 1;
    const int w0   = (rem & 1) << 6;
    const int lane = tid & 63;
    const int wv   = tid >> 6;          // wave = branch id (sobel,lap,diag,grad)
    const int l15  = lane & 15;
    const int quad = lane >> 4;
    const int ec   = tid & 31;          // E-compute: channel within chunk
    const int px0  = (tid >> 5) * 8;    // E-compute: 8-pixel group

    f32x4 acc[8][4];
#pragma unroll
    for (int i = 0; i < 8; ++i)
#pragma unroll
        for (int j = 0; j < 4; ++j) {
            f32x4 z = {0.f, 0.f, 0.f, 0.f};
            acc[i][j] = z;
        }

#pragma unroll 1
    for (int ch = 0; ch < 16; ++ch) {
        const int cbase = ch * 32;
        // ---- stage x tile: 32 ch x 3 rows x 68 cols, fp32 ----
        for (int i = tid; i < 6528; i += 256) {
            int c  = i / 204;
            int r2 = i - c * 204;
            int r  = r2 / 68;
            int d  = r2 - r * 68;
            int hg  = h + r - 1;
            int col = w0 - 2 + d;
            float val = 0.f;
            if (hg >= 0 && hg < 128 && col >= 0 && col < 128)
                val = x[(((b * 512 + cbase + c) * 128 + hg) << 7) + col];
            xs[c * XT_CS + r * XT_S + d] = val;
        }
        __syncthreads();
        // ---- compute E (sobel, lap, diag, grad) in fp32 -> El bf16 ----
        {
            const int base = ec * XT_CS;
#pragma unroll 1
            for (int i = 0; i < 8; ++i) {
                const int px = px0 + i;
                float v[3][3];
#pragma unroll
                for (int r = 0; r < 3; ++r)
#pragma unroll
                    for (int jj = 0; jj < 3; ++jj)
                        v[r][jj] = xs[base + r * XT_S + px + 1 + jj];
                float gh = (v[0][2] - v[0][0]) + 2.f * (v[1][2] - v[1][0]) + (v[2][2] - v[2][0]);
                float gv = (v[2][0] + 2.f * v[2][1] + v[2][2]) - (v[0][0] + 2.f * v[0][1] + v[0][2]);
                float lp = v[0][1] + v[1][0] + v[1][2] + v[2][1] - 4.f * v[1][1];
                float d1 = v[0][0] - v[0][2] - v[2][0] + v[2][2];
                float sob = sqrtf(gh * gh + gv * gv + 1e-8f);
                float lav = fabsf(lp);
                float dia = fabsf(d1);   // K_D2 == -K_D1 -> max(|d1|,|d2|) = |d1|
                float grd = sqrtf(sob * sob + lav * lav + 1e-8f);
                El[(0 * 64 + px) * ELS + ec] = f2bf(sob);
                El[(1 * 64 + px) * ELS + ec] = f2bf(lav);
                El[(2 * 64 + px) * ELS + ec] = f2bf(dia);
                El[(3 * 64 + px) * ELS + ec] = f2bf(grd);
            }
        }
        __syncthreads();
        // ---- per-wave GEMM (one 32-wide k-step): feat[o][px] += W[o][c]*E[px][c] ----
        {
            const int cg = quad * 8;    // k-offset within chunk
            bf16x8 bfr[4];
#pragma unroll
            for (int nt = 0; nt < 4; ++nt)
                bfr[nt] = *(const bf16x8*)&El[(wv * 64 + nt * 16 + l15) * ELS + cg];
#pragma unroll
            for (int mt = 0; mt < 8; ++mt) {
                bf16x8 a = *(const bf16x8*)&wBb[(size_t)(wv * 128 + mt * 16 + l15) * 512 + cbase + cg];
#pragma unroll
                for (int nt = 0; nt < 4; ++nt)
                    acc[mt][nt] = __builtin_amdgcn_mfma_f32_16x16x32_bf16(a, bfr[nt], acc[mt][nt], 0, 0, 0);
            }
        }
        __syncthreads();
    }
    // ---- epilogue: BN(eval) + GELU, pooled partials, LDS restage -> float4 stores ----
    const int pixbase = h * 128 + w0;
    float* wbuf = stg + wv * (16 * WBS);   // per-wave 16 rows * 68 fp32 (17408 B total)
#pragma unroll 1
    for (int mt = 0; mt < 8; ++mt) {
        const int ob = wv * 128 + mt * 16 + quad * 4;   // concat channel base for 4 regs
        float s[4], sh[4], ps[4];
#pragma unroll
        for (int r = 0; r < 4; ++r) {
            float sc = bg[ob + r] * 0.9999950000374997f;   // 1/sqrt(1+1e-5)
            s[r] = sc; sh[r] = bB[ob + r] * sc + bbt[ob + r]; ps[r] = 0.f;
        }
#pragma unroll
        for (int nt = 0; nt < 4; ++nt) {
            const int px = nt * 16 + l15;
#pragma unroll
            for (int r = 0; r < 4; ++r) {
                float y = acc[mt][nt][r] * s[r] + sh[r];
                float f = gelu_f(y);
                ps[r] += f;
                wbuf[(quad * 4 + r) * WBS + px] = f;    // LDS restage (wave-private, 2-way free)
            }
        }
#pragma unroll
        for (int r = 0; r < 4; ++r)
#pragma unroll
            for (int off = 1; off < 16; off <<= 1)
                ps[r] += __shfl_xor(ps[r], off, 64);
        if (l15 == 0) {
#pragma unroll
            for (int r = 0; r < 4; ++r)
                atomicAdd(&pooled[b * 512 + ob + r], ps[r]);
        }
        // 16 channel rows as 4 float4-store instructions (lane: row=g*4+quad, px=l15*4)
        const size_t rowbase = (size_t)(b * 512 + wv * 128 + mt * 16) * 16384 + pixbase;
#pragma unroll
        for (int g = 0; g < 4; ++g) {
            const int row = g * 4 + quad;
            f32x4 v = *(const f32x4*)&wbuf[row * WBS + l15 * 4];
            *(f32x4*)&ef[rowbase + (size_t)row * 16384 + l15 * 4] = v;
        }
    }
}

// ---------------- K2: SE attention (tiny, fp32) ----------------
__global__ void k2_att(const float* __restrict__ pooled,
                       const float* __restrict__ w1, const float* __restrict__ b1,
                       const float* __restrict__ w2, const float* __restrict__ b2,
                       float* __restrict__ att)
{
    __shared__ float pl[2048];
    __shared__ float hb[256];
    const int t = threadIdx.x;
    for (int i = t; i < 2048; i += 256) pl[i] = pooled[i] * (1.0f / 16384.0f);
    __syncthreads();
    {
        const int bb = t >> 6, e = t & 63;
        float a = b1[e];
        const float* wr = w1 + e * 512;
        for (int c = 0; c < 512; ++c)
            a += pl[bb * 512 + c] * wr[c];
        hb[t] = gelu_f(a);
    }
    __syncthreads();
    for (int i = t; i < 2048; i += 256) {
        const int bb = i >> 9, c = i & 511;
        const float* wr = w2 + c * 64;
        float a = b2[c];
        for (int e = 0; e < 64; ++e)
            a += hb[bb * 64 + e] * wr[e];
        att[i] = 1.0f / (1.0f + __expf(-a));
    }
}

// ---------------- K3: float4 stage -> LDS bf16 transpose, GEMM + LN + GELU + residual ----------------
#define L3W 260   // U32 per LDS pixel row (256 c-pairs + 4 pad; 1040 B)

__global__ __launch_bounds__(256, 2)
void k3_fuse(const float* __restrict__ ef, const float* __restrict__ att,
             const U16* __restrict__ wfb, const float* __restrict__ bfu,
             const float* __restrict__ lng, const float* __restrict__ lnb,
             const float* __restrict__ x, float* __restrict__ out)
{
    __shared__ U32 sh32[64 * L3W];          // 66560 B
    __shared__ float red_s[256];
    __shared__ float red_q[256];
    __shared__ float mu_s[64];
    __shared__ float iv_s[64];
    const int tid  = threadIdx.x, bi = blockIdx.x;
    const int b    = bi >> 8;
    const int pix0 = (bi & 255) << 6;
    const int lane = tid & 63, wv = tid >> 6;
    const int l15  = lane & 15, quad = lane >> 4;

    // ---- stage: row-wise float4 reads of ef [b][c][pix] (lane: pair=quad, px=l15*4;
    //      per instr 4 contiguous 256 B runs), scale by att, bf16-pack, transpose
    //      into LDS [px][c-pair]. Wave wv owns pairs [wv*64, wv*64+64).
#pragma unroll 2
    for (int it = 0; it < 16; ++it) {
        const int p  = wv * 64 + it * 4 + quad;   // c-pair index
        const int c0 = 2 * p;
        const float a0 = att[b * 512 + c0];
        const float a1 = att[b * 512 + c0 + 1];
        const float* rp = ef + (size_t)(b * 512 + c0) * 16384 + pix0 + l15 * 4;
        f32x4 v0 = *(const f32x4*)rp;
        f32x4 v1 = *(const f32x4*)(rp + 16384);
#pragma unroll
        for (int k = 0; k < 4; ++k)
            sh32[(l15 * 4 + k) * L3W + p] =
                (U32)f2bf(v0[k] * a0) | ((U32)f2bf(v1[k] * a1) << 16);
    }
    __syncthreads();

    f32x4 acc[4][8];
#pragma unroll
    for (int i = 0; i < 4; ++i)
#pragma unroll
        for (int j = 0; j < 8; ++j) {
            f32x4 z = {0.f, 0.f, 0.f, 0.f};
            acc[i][j] = z;
        }
#pragma unroll 1
    for (int ks = 0; ks < 16; ++ks) {
        const int cg = ks * 32 + quad * 8;
        bf16x8 a[4];
#pragma unroll
        for (int mt = 0; mt < 4; ++mt)
            a[mt] = *(const bf16x8*)&sh32[(mt * 16 + l15) * L3W + (cg >> 1)];
#pragma unroll
        for (int nt = 0; nt < 8; ++nt) {
            bf16x8 bw = *(const bf16x8*)&wfb[(size_t)(wv * 128 + nt * 16 + l15) * 512 + cg];
#pragma unroll
            for (int mt = 0; mt < 4; ++mt)
                acc[mt][nt] = __builtin_amdgcn_mfma_f32_16x16x32_bf16(a[mt], bw, acc[mt][nt], 0, 0, 0);
        }
    }
    // bias then LN stats (sum, sumsq over all 512 channels per pixel)
#pragma unroll
    for (int nt = 0; nt < 8; ++nt) {
        const float bz = bfu[wv * 128 + nt * 16 + l15];
#pragma unroll
        for (int mt = 0; mt < 4; ++mt)
#pragma unroll
            for (int r = 0; r < 4; ++r)
                acc[mt][nt][r] += bz;
    }
#pragma unroll
    for (int mt = 0; mt < 4; ++mt)
#pragma unroll
        for (int r = 0; r < 4; ++r) {
            float s = 0.f, q = 0.f;
#pragma unroll
            for (int nt = 0; nt < 8; ++nt) {
                float v = acc[mt][nt][r];
                s += v; q += v * v;
            }
#pragma unroll
            for (int off = 1; off < 16; off <<= 1) {
                s += __shfl_xor(s, off, 64);
                q += __shfl_xor(q, off, 64);
            }
            if (l15 == 0) {
                const int p = mt * 16 + quad * 4 + r;
                red_s[p * 4 + wv] = s;
                red_q[p * 4 + wv] = q;
            }
        }
    __syncthreads();
    if (tid < 64) {
        float S = red_s[tid * 4] + red_s[tid * 4 + 1] + red_s[tid * 4 + 2] + red_s[tid * 4 + 3];
        float Q = red_q[tid * 4] + red_q[tid * 4 + 1] + red_q[tid * 4 + 2] + red_q[tid * 4 + 3];
        float mu  = S * (1.0f / 512.0f);
        float var = fmaxf(Q * (1.0f / 512.0f) - mu * mu, 0.0f);
        mu_s[tid] = mu;
        iv_s[tid] = rsqrtf(var + 1e-6f);
    }
    __syncthreads();
    // ---- epilogue: LN + GELU + residual, DIRECT float4 stores from acc ----
    // acc layout: lane (l15,quad) holds channel o=wv*128+nt*16+l15, pixels
    // mt*16+quad*4 .. +3 -> one lane's 4 regs = 4 consecutive pixels = float4.
#pragma unroll 1
    for (int nt = 0; nt < 8; ++nt) {
        const int o = wv * 128 + nt * 16 + l15;
        const float g  = lng[o];
        const float be = lnb[o];
        const size_t rowoff = (size_t)(b * 512 + o) * 16384 + pix0;
#pragma unroll
        for (int mt = 0; mt < 4; ++mt) {
            const int pb = mt * 16 + quad * 4;
            f32x4 xv = *(const f32x4*)&x[rowoff + pb];
            f32x4 ov;
#pragma unroll
            for (int r = 0; r < 4; ++r) {
                const int p = pb + r;
                float z = (acc[mt][nt][r] - mu_s[p]) * iv_s[p];
                float y = z * g + be;
                ov[r] = gelu_f(y) + xv[r];
            }
            *(f32x4*)&out[rowoff + pb] = ov;
        }
    }
}

extern "C" void kernel_launch(void* const* d_in, const int* in_sizes, int n_in,
                              void* d_out, int out_size, void* d_ws, size_t ws_size,
                              hipStream_t stream)
{
    const float* x   = (const float*)d_in[0];
    const float* wB  = (const float*)d_in[1];
    const float* bB  = (const float*)d_in[2];
    const float* bg  = (const float*)d_in[3];
    const float* bbt = (const float*)d_in[4];
    const float* w1  = (const float*)d_in[5];
    const float* b1  = (const float*)d_in[6];
    const float* w2  = (const float*)d_in[7];
    const float* b2  = (const float*)d_in[8];
    const float* wf  = (const float*)d_in[9];
    const float* bfu = (const float*)d_in[10];
    const float* lng = (const float*)d_in[11];
    const float* lnb = (const float*)d_in[12];
    float* out = (float*)d_out;

    // d_ws layout: pooled 8K | att 8K | wBb 512K | wfb 512K | ef 128M (if it fits)
    float* pooled = (float*)d_ws;
    float* att    = (float*)((char*)d_ws + 8192);
    U16*   wBb    = (U16*)((char*)d_ws + 16384);
    U16*   wfb    = (U16*)((char*)d_ws + 16384 + 524288);
    const size_t EF_OFF  = 16384 + 2 * 524288;              // 1064960 B (16B-aligned)
    const size_t EF_SIZE = (size_t)4 * 512 * 16384 * 4;     // 134217728 B
    // DECISIVE EXPERIMENT: ef in d_ws (cached coarse-grained device mem) vs d_out.
    // Theory: d_out is fine-grained/write-through -> per-lane 64B EA beats, no L2
    // write-combining (WRITE_SIZE invariant at 18x data). d_ws should behave like d_in.
    float* ef = (ws_size >= EF_OFF + EF_SIZE) ? (float*)((char*)d_ws + EF_OFF) : out;

    hipMemsetAsync(pooled, 0, 2048 * sizeof(float), stream);
    hipLaunchKernelGGL(k0_cvt, dim3(1024), dim3(256), 0, stream, wB, wf, wBb, wfb);
    hipLaunchKernelGGL(k1_branch, dim3(1024), dim3(256), 0, stream,
                       x, wBb, bB, bg, bbt, ef, pooled);
    hipLaunchKernelGGL(k2_att, dim3(1), dim3(256), 0, stream,
                       pooled, w1, b1, w2, b2, att);
    hipLaunchKernelGGL(k3_fuse, dim3(1024), dim3(256), 0, stream,
                       ef, att, wfb, bfu, lng, lnb, x, out);
}

// Round 4
// 938.363 us; speedup vs baseline: 1.5323x; 1.5323x over previous
//
#include <hip/hip_runtime.h>
#include <math.h>

typedef unsigned short U16;
typedef unsigned int   U32;
typedef __attribute__((ext_vector_type(8))) __bf16 bf16x8;
typedef __attribute__((ext_vector_type(4))) float  f32x4;

__device__ __forceinline__ U16 f2bf(float f) {
    __bf16 h = (__bf16)f;
    return __builtin_bit_cast(U16, h);
}
__device__ __forceinline__ float gelu_f(float y) {
    return 0.5f * y * (1.0f + erff(y * 0.70710678118654752f));
}

#define XT_S  69     // fp32 x-tile row stride (68 cols + 1 pad)
#define XT_CS 207    // 3 * XT_S, per-channel stride
#define ELS   40     // El per-pixel channel stride (32 ch + 8 pad) -> 80 B, 16B-aligned
#define WBS   68     // epilogue restage row stride (even mult of 4 -> 16B-aligned float4)

// ---------------- K0: one-time weight fp32 -> bf16 conversion ----------------
__global__ void k0_cvt(const float* __restrict__ wB, const float* __restrict__ wf,
                       U16* __restrict__ wBb, U16* __restrict__ wfb)
{
    const int i = blockIdx.x * 256 + threadIdx.x;   // 1024 blocks -> 262144 = both sizes
    wBb[i] = f2bf(wB[i]);
    wfb[i] = f2bf(wf[i]);
}

// ---------------- K1: edge maps + 4 branch GEMMs + BN + GELU + pooled ----------------
// CRITICAL: every access to acc[][] must be compile-time-indexed (fully unrolled
// loops). A single runtime index defeats SROA and demotes the whole accumulator
// to scratch -> 2.3 GB of hidden scratch write-backs (the Round-0..3 mystery).
__global__ __launch_bounds__(256, 2)
void k1_branch(const float* __restrict__ x, const U16* __restrict__ wBb,
               const float* __restrict__ bB, const float* __restrict__ bg,
               const float* __restrict__ bbt, float* __restrict__ ef,
               float* __restrict__ pooled)
{
    __shared__ __align__(16) char smem[46976];
    float* xs  = (float*)smem;                 // 32*207 fp32 = 26496 B
    U16*   El  = (U16*)(smem + 26496);         // 4*64*40 U16 = 20480 B
    float* stg = (float*)(smem + 26496);       // epilogue: aliases El (dead after k-loop)

    const int tid  = threadIdx.x;
    // bijective chunked XCD swizzle: dispatch p -> XCD p%8; each XCD gets a
    // contiguous 128-block chunk so h-adjacent blocks share an L2 (halo reuse).
    const int bi   = ((blockIdx.x & 7) << 7) | (blockIdx.x >> 3);
    const int b    = bi >> 8;
    const int rem  = bi & 255;
    const int h    = rem >> 1;
    const int w0   = (rem & 1) << 6;
    const int lane = tid & 63;
    const int wv   = tid >> 6;          // wave = branch id (sobel,lap,diag,grad)
    const int l15  = lane & 15;
    const int quad = lane >> 4;
    const int ec   = tid & 31;          // E-compute: channel within chunk
    const int px0  = (tid >> 5) * 8;    // E-compute: 8-pixel group

    f32x4 acc[8][4];
#pragma unroll
    for (int i = 0; i < 8; ++i)
#pragma unroll
        for (int j = 0; j < 4; ++j) {
            f32x4 z = {0.f, 0.f, 0.f, 0.f};
            acc[i][j] = z;
        }

#pragma unroll 1
    for (int ch = 0; ch < 16; ++ch) {
        const int cbase = ch * 32;
        // ---- stage x tile: 32 ch x 3 rows x 68 cols, fp32 ----
        for (int i = tid; i < 6528; i += 256) {
            int c  = i / 204;
            int r2 = i - c * 204;
            int r  = r2 / 68;
            int d  = r2 - r * 68;
            int hg  = h + r - 1;
            int col = w0 - 2 + d;
            float val = 0.f;
            if (hg >= 0 && hg < 128 && col >= 0 && col < 128)
                val = x[(((b * 512 + cbase + c) * 128 + hg) << 7) + col];
            xs[c * XT_CS + r * XT_S + d] = val;
        }
        __syncthreads();
        // ---- compute E (sobel, lap, diag, grad) in fp32 -> El bf16 ----
        {
            const int base = ec * XT_CS;
#pragma unroll 1
            for (int i = 0; i < 8; ++i) {
                const int px = px0 + i;
                float v[3][3];
#pragma unroll
                for (int r = 0; r < 3; ++r)
#pragma unroll
                    for (int jj = 0; jj < 3; ++jj)
                        v[r][jj] = xs[base + r * XT_S + px + 1 + jj];
                float gh = (v[0][2] - v[0][0]) + 2.f * (v[1][2] - v[1][0]) + (v[2][2] - v[2][0]);
                float gv = (v[2][0] + 2.f * v[2][1] + v[2][2]) - (v[0][0] + 2.f * v[0][1] + v[0][2]);
                float lp = v[0][1] + v[1][0] + v[1][2] + v[2][1] - 4.f * v[1][1];
                float d1 = v[0][0] - v[0][2] - v[2][0] + v[2][2];
                float sob = sqrtf(gh * gh + gv * gv + 1e-8f);
                float lav = fabsf(lp);
                float dia = fabsf(d1);   // K_D2 == -K_D1 -> max(|d1|,|d2|) = |d1|
                float grd = sqrtf(sob * sob + lav * lav + 1e-8f);
                El[(0 * 64 + px) * ELS + ec] = f2bf(sob);
                El[(1 * 64 + px) * ELS + ec] = f2bf(lav);
                El[(2 * 64 + px) * ELS + ec] = f2bf(dia);
                El[(3 * 64 + px) * ELS + ec] = f2bf(grd);
            }
        }
        __syncthreads();
        // ---- per-wave GEMM (one 32-wide k-step): feat[o][px] += W[o][c]*E[px][c] ----
        {
            const int cg = quad * 8;    // k-offset within chunk
            bf16x8 bfr[4];
#pragma unroll
            for (int nt = 0; nt < 4; ++nt)
                bfr[nt] = *(const bf16x8*)&El[(wv * 64 + nt * 16 + l15) * ELS + cg];
#pragma unroll
            for (int mt = 0; mt < 8; ++mt) {
                bf16x8 a = *(const bf16x8*)&wBb[(size_t)(wv * 128 + mt * 16 + l15) * 512 + cbase + cg];
#pragma unroll
                for (int nt = 0; nt < 4; ++nt)
                    acc[mt][nt] = __builtin_amdgcn_mfma_f32_16x16x32_bf16(a, bfr[nt], acc[mt][nt], 0, 0, 0);
            }
        }
        __syncthreads();
    }
    // ---- epilogue: BN(eval) + GELU, pooled partials, LDS restage -> float4 stores ----
    // FULLY UNROLLED mt loop: acc[mt] must be a compile-time index (SROA / rule #20).
    const int pixbase = h * 128 + w0;
    float* wbuf = stg + wv * (16 * WBS);   // per-wave 16 rows * 68 fp32 (17408 B total)
#pragma unroll
    for (int mt = 0; mt < 8; ++mt) {
        const int ob = wv * 128 + mt * 16 + quad * 4;   // concat channel base for 4 regs
        float s[4], sh[4], ps[4];
#pragma unroll
        for (int r = 0; r < 4; ++r) {
            float sc = bg[ob + r] * 0.9999950000374997f;   // 1/sqrt(1+1e-5)
            s[r] = sc; sh[r] = bB[ob + r] * sc + bbt[ob + r]; ps[r] = 0.f;
        }
#pragma unroll
        for (int nt = 0; nt < 4; ++nt) {
            const int px = nt * 16 + l15;
#pragma unroll
            for (int r = 0; r < 4; ++r) {
                float y = acc[mt][nt][r] * s[r] + sh[r];
                float f = gelu_f(y);
                ps[r] += f;
                wbuf[(quad * 4 + r) * WBS + px] = f;    // LDS restage (wave-private)
            }
        }
#pragma unroll
        for (int r = 0; r < 4; ++r)
#pragma unroll
            for (int off = 1; off < 16; off <<= 1)
                ps[r] += __shfl_xor(ps[r], off, 64);
        if (l15 == 0) {
#pragma unroll
            for (int r = 0; r < 4; ++r)
                atomicAdd(&pooled[b * 512 + ob + r], ps[r]);
        }
        // 16 channel rows as 4 float4-store instructions (lane: row=g*4+quad, px=l15*4)
        const size_t rowbase = (size_t)(b * 512 + wv * 128 + mt * 16) * 16384 + pixbase;
#pragma unroll
        for (int g = 0; g < 4; ++g) {
            const int row = g * 4 + quad;
            f32x4 v = *(const f32x4*)&wbuf[row * WBS + l15 * 4];
            *(f32x4*)&ef[rowbase + (size_t)row * 16384 + l15 * 4] = v;
        }
    }
}

// ---------------- K2: SE attention (tiny, fp32) ----------------
__global__ void k2_att(const float* __restrict__ pooled,
                       const float* __restrict__ w1, const float* __restrict__ b1,
                       const float* __restrict__ w2, const float* __restrict__ b2,
                       float* __restrict__ att)
{
    __shared__ float pl[2048];
    __shared__ float hb[256];
    const int t = threadIdx.x;
    for (int i = t; i < 2048; i += 256) pl[i] = pooled[i] * (1.0f / 16384.0f);
    __syncthreads();
    {
        const int bb = t >> 6, e = t & 63;
        float a = b1[e];
        const float* wr = w1 + e * 512;
        for (int c = 0; c < 512; ++c)
            a += pl[bb * 512 + c] * wr[c];
        hb[t] = gelu_f(a);
    }
    __syncthreads();
    for (int i = t; i < 2048; i += 256) {
        const int bb = i >> 9, c = i & 511;
        const float* wr = w2 + c * 64;
        float a = b2[c];
        for (int e = 0; e < 64; ++e)
            a += hb[bb * 64 + e] * wr[e];
        att[i] = 1.0f / (1.0f + __expf(-a));
    }
}

// ---------------- K3: float4 stage -> LDS bf16 transpose, GEMM + LN + GELU + residual ----------------
#define L3W 260   // U32 per LDS pixel row (256 c-pairs + 4 pad; 1040 B)

__global__ __launch_bounds__(256, 2)
void k3_fuse(const float* __restrict__ ef, const float* __restrict__ att,
             const U16* __restrict__ wfb, const float* __restrict__ bfu,
             const float* __restrict__ lng, const float* __restrict__ lnb,
             const float* __restrict__ x, float* __restrict__ out)
{
    __shared__ U32 sh32[64 * L3W];          // 66560 B
    __shared__ float red_s[256];
    __shared__ float red_q[256];
    __shared__ float mu_s[64];
    __shared__ float iv_s[64];
    const int tid  = threadIdx.x, bi = blockIdx.x;
    const int b    = bi >> 8;
    const int pix0 = (bi & 255) << 6;
    const int lane = tid & 63, wv = tid >> 6;
    const int l15  = lane & 15, quad = lane >> 4;

    // ---- stage: row-wise float4 reads of ef [b][c][pix] (lane: pair=quad, px=l15*4;
    //      per instr 4 contiguous 256 B runs), scale by att, bf16-pack, transpose
    //      into LDS [px][c-pair]. Wave wv owns pairs [wv*64, wv*64+64).
#pragma unroll 2
    for (int it = 0; it < 16; ++it) {
        const int p  = wv * 64 + it * 4 + quad;   // c-pair index
        const int c0 = 2 * p;
        const float a0 = att[b * 512 + c0];
        const float a1 = att[b * 512 + c0 + 1];
        const float* rp = ef + (size_t)(b * 512 + c0) * 16384 + pix0 + l15 * 4;
        f32x4 v0 = *(const f32x4*)rp;
        f32x4 v1 = *(const f32x4*)(rp + 16384);
#pragma unroll
        for (int k = 0; k < 4; ++k)
            sh32[(l15 * 4 + k) * L3W + p] =
                (U32)f2bf(v0[k] * a0) | ((U32)f2bf(v1[k] * a1) << 16);
    }
    __syncthreads();

    f32x4 acc[4][8];
#pragma unroll
    for (int i = 0; i < 4; ++i)
#pragma unroll
        for (int j = 0; j < 8; ++j) {
            f32x4 z = {0.f, 0.f, 0.f, 0.f};
            acc[i][j] = z;
        }
#pragma unroll 1
    for (int ks = 0; ks < 16; ++ks) {
        const int cg = ks * 32 + quad * 8;
        bf16x8 a[4];
#pragma unroll
        for (int mt = 0; mt < 4; ++mt)
            a[mt] = *(const bf16x8*)&sh32[(mt * 16 + l15) * L3W + (cg >> 1)];
#pragma unroll
        for (int nt = 0; nt < 8; ++nt) {
            bf16x8 bw = *(const bf16x8*)&wfb[(size_t)(wv * 128 + nt * 16 + l15) * 512 + cg];
#pragma unroll
            for (int mt = 0; mt < 4; ++mt)
                acc[mt][nt] = __builtin_amdgcn_mfma_f32_16x16x32_bf16(a[mt], bw, acc[mt][nt], 0, 0, 0);
        }
    }
    // bias then LN stats (sum, sumsq over all 512 channels per pixel)
#pragma unroll
    for (int nt = 0; nt < 8; ++nt) {
        const float bz = bfu[wv * 128 + nt * 16 + l15];
#pragma unroll
        for (int mt = 0; mt < 4; ++mt)
#pragma unroll
            for (int r = 0; r < 4; ++r)
                acc[mt][nt][r] += bz;
    }
#pragma unroll
    for (int mt = 0; mt < 4; ++mt)
#pragma unroll
        for (int r = 0; r < 4; ++r) {
            float s = 0.f, q = 0.f;
#pragma unroll
            for (int nt = 0; nt < 8; ++nt) {
                float v = acc[mt][nt][r];
                s += v; q += v * v;
            }
#pragma unroll
            for (int off = 1; off < 16; off <<= 1) {
                s += __shfl_xor(s, off, 64);
                q += __shfl_xor(q, off, 64);
            }
            if (l15 == 0) {
                const int p = mt * 16 + quad * 4 + r;
                red_s[p * 4 + wv] = s;
                red_q[p * 4 + wv] = q;
            }
        }
    __syncthreads();
    if (tid < 64) {
        float S = red_s[tid * 4] + red_s[tid * 4 + 1] + red_s[tid * 4 + 2] + red_s[tid * 4 + 3];
        float Q = red_q[tid * 4] + red_q[tid * 4 + 1] + red_q[tid * 4 + 2] + red_q[tid * 4 + 3];
        float mu  = S * (1.0f / 512.0f);
        float var = fmaxf(Q * (1.0f / 512.0f) - mu * mu, 0.0f);
        mu_s[tid] = mu;
        iv_s[tid] = rsqrtf(var + 1e-6f);
    }
    __syncthreads();
    // ---- epilogue: LN + GELU + residual, DIRECT float4 stores from acc ----
    // FULLY UNROLLED nt loop: acc[mt][nt] must be compile-time-indexed (SROA).
    // acc layout: lane (l15,quad) holds channel o=wv*128+nt*16+l15, pixels
    // mt*16+quad*4 .. +3 -> one lane's 4 regs = 4 consecutive pixels = float4.
#pragma unroll
    for (int nt = 0; nt < 8; ++nt) {
        const int o = wv * 128 + nt * 16 + l15;
        const float g  = lng[o];
        const float be = lnb[o];
        const size_t rowoff = (size_t)(b * 512 + o) * 16384 + pix0;
#pragma unroll
        for (int mt = 0; mt < 4; ++mt) {
            const int pb = mt * 16 + quad * 4;
            f32x4 xv = *(const f32x4*)&x[rowoff + pb];
            f32x4 ov;
#pragma unroll
            for (int r = 0; r < 4; ++r) {
                const int p = pb + r;
                float z = (acc[mt][nt][r] - mu_s[p]) * iv_s[p];
                float y = z * g + be;
                ov[r] = gelu_f(y) + xv[r];
            }
            *(f32x4*)&out[rowoff + pb] = ov;
        }
    }
}

extern "C" void kernel_launch(void* const* d_in, const int* in_sizes, int n_in,
                              void* d_out, int out_size, void* d_ws, size_t ws_size,
                              hipStream_t stream)
{
    const float* x   = (const float*)d_in[0];
    const float* wB  = (const float*)d_in[1];
    const float* bB  = (const float*)d_in[2];
    const float* bg  = (const float*)d_in[3];
    const float* bbt = (const float*)d_in[4];
    const float* w1  = (const float*)d_in[5];
    const float* b1  = (const float*)d_in[6];
    const float* w2  = (const float*)d_in[7];
    const float* b2  = (const float*)d_in[8];
    const float* wf  = (const float*)d_in[9];
    const float* bfu = (const float*)d_in[10];
    const float* lng = (const float*)d_in[11];
    const float* lnb = (const float*)d_in[12];
    float* out = (float*)d_out;

    // d_ws layout: pooled 8K | att 8K | wBb 512K | wfb 512K | ef 128M (if it fits)
    float* pooled = (float*)d_ws;
    float* att    = (float*)((char*)d_ws + 8192);
    U16*   wBb    = (U16*)((char*)d_ws + 16384);
    U16*   wfb    = (U16*)((char*)d_ws + 16384 + 524288);
    const size_t EF_OFF  = 16384 + 2 * 524288;              // 1064960 B (16B-aligned)
    const size_t EF_SIZE = (size_t)4 * 512 * 16384 * 4;     // 134217728 B
    float* ef = (ws_size >= EF_OFF + EF_SIZE) ? (float*)((char*)d_ws + EF_OFF) : out;

    hipMemsetAsync(pooled, 0, 2048 * sizeof(float), stream);
    hipLaunchKernelGGL(k0_cvt, dim3(1024), dim3(256), 0, stream, wB, wf, wBb, wfb);
    hipLaunchKernelGGL(k1_branch, dim3(1024), dim3(256), 0, stream,
                       x, wBb, bB, bg, bbt, ef, pooled);
    hipLaunchKernelGGL(k2_att, dim3(1), dim3(256), 0, stream,
                       pooled, w1, b1, w2, b2, att);
    hipLaunchKernelGGL(k3_fuse, dim3(1024), dim3(256), 0, stream,
                       ef, att, wfb, bfu, lng, lnb, x, out);
}

// Round 6
// 584.260 us; speedup vs baseline: 2.4610x; 1.6061x over previous
//
#include <hip/hip_runtime.h>
#include <math.h>

typedef unsigned short U16;
typedef unsigned int   U32;
typedef __attribute__((ext_vector_type(8))) __bf16 bf16x8;
typedef __attribute__((ext_vector_type(4))) float  f32x4;

__device__ __forceinline__ U16 f2bf(float f) {
    __bf16 h = (__bf16)f;
    return __builtin_bit_cast(U16, h);
}
__device__ __forceinline__ float gelu_f(float y) {
    return 0.5f * y * (1.0f + erff(y * 0.70710678118654752f));
}
// async global->LDS, 4 B per lane, dest = wave-uniform base + lane*4 (linear)
__device__ __forceinline__ void gl_lds4(const void* g, void* l) {
    __builtin_amdgcn_global_load_lds((const __attribute__((address_space(1))) void*)g,
                                     (__attribute__((address_space(3))) void*)l, 4, 0, 0);
}

#define XT_S  68     // x-tile row stride (68 cols, 16B-mult)
#define XT_CS 212    // per-channel stride = 3*68 + 8 pad (212/4=53 odd -> b128 bank-friendly)
#define XBUF  6784   // floats per x buffer = 32*212
#define ELS   40     // El per-pixel channel stride (32 ch + 8 pad)
#define WBS   68     // epilogue restage row stride

// ---------------- K0: one-time weight fp32 -> bf16 conversion ----------------
__global__ void k0_cvt(const float* __restrict__ wB, const float* __restrict__ wf,
                       U16* __restrict__ wBb, U16* __restrict__ wfb)
{
    const int i = blockIdx.x * 256 + threadIdx.x;   // 1024 blocks -> 262144 = both sizes
    wBb[i] = f2bf(wB[i]);
    wfb[i] = f2bf(wf[i]);
}

// ---------------- K1: edge maps + 4 branch GEMMs + BN + GELU + pooled ----------------
// Double-buffered global_load_lds staging (prefetch chunk ch+1 during compute of ch),
// vectorized b128 E-compute. All acc[][] accesses compile-time-indexed (rule #20).
__global__ __launch_bounds__(256, 2)
void k1_branch(const float* __restrict__ x, const U16* __restrict__ wBb,
               const float* __restrict__ bB, const float* __restrict__ bg,
               const float* __restrict__ bbt, const float* __restrict__ zb,
               float* __restrict__ ef, float* __restrict__ pooled)
{
    __shared__ __align__(16) char smem[74752];
    float* xs  = (float*)smem;                 // 2 x 27136 B x-buffers
    U16*   El  = (U16*)(smem + 54272);         // 20480 B
    float* stg = (float*)(smem + 54272);       // epilogue alias (dead after k-loop)

    const int tid  = threadIdx.x;
    // bijective chunked XCD swizzle (h-adjacent blocks share an L2)
    const int bi   = ((blockIdx.x & 7) << 7) | (blockIdx.x >> 3);
    const int b    = bi >> 8;
    const int rem  = bi & 255;
    const int h    = rem >> 1;
    const int w0   = (rem & 1) << 6;
    const int lane = tid & 63;
    const int wv   = tid >> 6;
    const int l15  = lane & 15;
    const int quad = lane >> 4;
    const int ec   = tid & 31;
    const int px0  = (tid >> 5) * 8;
    const int hm = (h - 1) * 128, hc = h * 128, hp = (h + 1) * 128;

    f32x4 acc[8][4];
#pragma unroll
    for (int i = 0; i < 8; ++i)
#pragma unroll
        for (int j = 0; j < 4; ++j) {
            f32x4 z = {0.f, 0.f, 0.f, 0.f};
            acc[i][j] = z;
        }

    // stage chunk chk (32 channels) into buffer bs
    auto stage = [&](int chk, int bs) {
        const int cb = chk * 32;
        float* xb = xs + bs * XBUF;
        // ---- halo scalar loads first (oldest vmcnt entries) ----
        float hv0 = 0.f, hv1 = 0.f;
        int ha0, ha1 = -1;
        {
            int row = tid >> 2, k = tid & 3;
            int c = (row * 171) >> 9, r = row - c * 3;
            int d = (k < 2) ? k : 64 + k;
            int col = w0 - 2 + d, hg = h + r - 1;
            ha0 = c * XT_CS + r * XT_S + d;
            if (hg >= 0 && hg < 128 && col >= 0 && col < 128)
                hv0 = x[(size_t)(b * 512 + cb + c) * 16384 + hg * 128 + col];
        }
        if (tid < 128) {
            int e = tid + 256;
            int row = e >> 2, k = e & 3;
            int c = (row * 171) >> 9, r = row - c * 3;
            int d = (k < 2) ? k : 64 + k;
            int col = w0 - 2 + d, hg = h + r - 1;
            ha1 = c * XT_CS + r * XT_S + d;
            if (hg >= 0 && hg < 128 && col >= 0 && col < 128)
                hv1 = x[(size_t)(b * 512 + cb + c) * 16384 + hg * 128 + col];
        }
        // ---- interior: 24 rows per wave via global_load_lds (64 cols each) ----
        const float* xrow = x + (size_t)(b * 512 + cb + wv * 8) * 16384 + w0 + lane;
        const float* zbl  = zb + lane;
        float* xw = xb + wv * 8 * XT_CS;
#pragma unroll
        for (int j = 0; j < 24; ++j) {
            const int cl = j / 3, r = j - (j / 3) * 3;
            float* dst = xw + cl * XT_CS + r * XT_S + 2;
            const float* src;
            if (r == 0)      src = (h == 0)   ? zbl : xrow + cl * 16384 + hm;
            else if (r == 1) src =                    xrow + cl * 16384 + hc;
            else             src = (h == 127) ? zbl : xrow + cl * 16384 + hp;
            gl_lds4(src, dst);
        }
        // ---- halo writes (compiler waits only the 2 scalar loads) ----
        xb[ha0] = hv0;
        if (ha1 >= 0) xb[ha1] = hv1;
    };

    stage(0, 0);
    __syncthreads();

#pragma unroll 1
    for (int ch = 0; ch < 16; ++ch) {
        const int cur = ch & 1;
        if (ch < 15) stage(ch + 1, cur ^ 1);   // prefetch: latency hides under E-compute
        // ---- E-compute (vectorized): 2 halves of 4 px, b128 window reads ----
        {
            const float* xc = xs + cur * XBUF + ec * XT_CS;
#pragma unroll
            for (int hh = 0; hh < 2; ++hh) {
                const int pb = px0 + hh * 4;
                float wr[3][8];
#pragma unroll
                for (int r = 0; r < 3; ++r) {
                    f32x4 A = *(const f32x4*)(xc + r * XT_S + pb);
                    f32x4 B = *(const f32x4*)(xc + r * XT_S + pb + 4);
#pragma unroll
                    for (int q = 0; q < 4; ++q) { wr[r][q] = A[q]; wr[r][4 + q] = B[q]; }
                }
#pragma unroll
                for (int i = 0; i < 4; ++i) {
                    const int px = pb + i;
                    float v00 = wr[0][i + 1], v01 = wr[0][i + 2], v02 = wr[0][i + 3];
                    float v10 = wr[1][i + 1], v11 = wr[1][i + 2], v12 = wr[1][i + 3];
                    float v20 = wr[2][i + 1], v21 = wr[2][i + 2], v22 = wr[2][i + 3];
                    float gh = (v02 - v00) + 2.f * (v12 - v10) + (v22 - v20);
                    float gv = (v20 + 2.f * v21 + v22) - (v00 + 2.f * v01 + v02);
                    float lp = v01 + v10 + v12 + v21 - 4.f * v11;
                    float d1 = v00 - v02 - v20 + v22;
                    float sob = sqrtf(gh * gh + gv * gv + 1e-8f);
                    float lav = fabsf(lp);
                    float dia = fabsf(d1);   // K_D2 == -K_D1
                    float grd = sqrtf(sob * sob + lav * lav + 1e-8f);
                    El[(0 * 64 + px) * ELS + ec] = f2bf(sob);
                    El[(1 * 64 + px) * ELS + ec] = f2bf(lav);
                    El[(2 * 64 + px) * ELS + ec] = f2bf(dia);
                    El[(3 * 64 + px) * ELS + ec] = f2bf(grd);
                }
            }
        }
        __syncthreads();
        // ---- per-wave GEMM: one 32-wide k-step ----
        {
            const int cbase = ch * 32;
            const int cg = quad * 8;
            bf16x8 bfr[4];
#pragma unroll
            for (int nt = 0; nt < 4; ++nt)
                bfr[nt] = *(const bf16x8*)&El[(wv * 64 + nt * 16 + l15) * ELS + cg];
#pragma unroll
            for (int mt = 0; mt < 8; ++mt) {
                bf16x8 a = *(const bf16x8*)&wBb[(size_t)(wv * 128 + mt * 16 + l15) * 512 + cbase + cg];
#pragma unroll
                for (int nt = 0; nt < 4; ++nt)
                    acc[mt][nt] = __builtin_amdgcn_mfma_f32_16x16x32_bf16(a, bfr[nt], acc[mt][nt], 0, 0, 0);
            }
        }
        __syncthreads();   // El WAR + drains prefetch gll for next chunk
    }

    // ---- epilogue: BN(eval) + GELU, pooled partials, LDS restage -> float4 stores ----
    const int pixbase = h * 128 + w0;
    float* wbuf = stg + wv * (16 * WBS);
#pragma unroll
    for (int mt = 0; mt < 8; ++mt) {
        const int ob = wv * 128 + mt * 16 + quad * 4;
        float s[4], sh[4], ps[4];
#pragma unroll
        for (int r = 0; r < 4; ++r) {
            float sc = bg[ob + r] * 0.9999950000374997f;   // 1/sqrt(1+1e-5)
            s[r] = sc; sh[r] = bB[ob + r] * sc + bbt[ob + r]; ps[r] = 0.f;
        }
#pragma unroll
        for (int nt = 0; nt < 4; ++nt) {
            const int px = nt * 16 + l15;
#pragma unroll
            for (int r = 0; r < 4; ++r) {
                float y = acc[mt][nt][r] * s[r] + sh[r];
                float f = gelu_f(y);
                ps[r] += f;
                wbuf[(quad * 4 + r) * WBS + px] = f;
            }
        }
#pragma unroll
        for (int r = 0; r < 4; ++r)
#pragma unroll
            for (int off = 1; off < 16; off <<= 1)
                ps[r] += __shfl_xor(ps[r], off, 64);
        if (l15 == 0) {
#pragma unroll
            for (int r = 0; r < 4; ++r)
                atomicAdd(&pooled[b * 512 + ob + r], ps[r]);
        }
        const size_t rowbase = (size_t)(b * 512 + wv * 128 + mt * 16) * 16384 + pixbase;
#pragma unroll
        for (int g = 0; g < 4; ++g) {
            const int row = g * 4 + quad;
            f32x4 v = *(const f32x4*)&wbuf[row * WBS + l15 * 4];
            *(f32x4*)&ef[rowbase + (size_t)row * 16384 + l15 * 4] = v;
        }
    }
}

// ---------------- K2: SE attention (tiny, fp32) ----------------
__global__ void k2_att(const float* __restrict__ pooled,
                       const float* __restrict__ w1, const float* __restrict__ b1,
                       const float* __restrict__ w2, const float* __restrict__ b2,
                       float* __restrict__ att)
{
    __shared__ float pl[2048];
    __shared__ float hb[256];
    const int t = threadIdx.x;
    for (int i = t; i < 2048; i += 256) pl[i] = pooled[i] * (1.0f / 16384.0f);
    __syncthreads();
    {
        const int bb = t >> 6, e = t & 63;
        float a = b1[e];
        const float* wr = w1 + e * 512;
        for (int c = 0; c < 512; ++c)
            a += pl[bb * 512 + c] * wr[c];
        hb[t] = gelu_f(a);
    }
    __syncthreads();
    for (int i = t; i < 2048; i += 256) {
        const int bb = i >> 9, c = i & 511;
        const float* wr = w2 + c * 64;
        float a = b2[c];
        for (int e = 0; e < 64; ++e)
            a += hb[bb * 64 + e] * wr[e];
        att[i] = 1.0f / (1.0f + __expf(-a));
    }
}

// ---------------- K3: chunked double-buffered stage (input + weights in LDS),
//                  GEMM + LN + GELU + residual ----------------
#define KP 20   // U32 per px row per chunk (16 pairs + 4 pad; 80 B, 16B-mult)

__global__ __launch_bounds__(256, 2)
void k3_fuse(const float* __restrict__ ef, const float* __restrict__ att,
             const U16* __restrict__ wfb, const float* __restrict__ bfu,
             const float* __restrict__ lng, const float* __restrict__ lnb,
             const float* __restrict__ x, float* __restrict__ out)
{
    __shared__ __align__(16) U32 kb[2][64 * KP];    // 10240 B input chunks
    __shared__ __align__(16) U16 wl[2][512 * 32];   // 65536 B weight chunks
    __shared__ float red_s[256];
    __shared__ float red_q[256];
    __shared__ float mu_s[64];
    __shared__ float iv_s[64];
    const int tid  = threadIdx.x, bi = blockIdx.x;
    const int b    = bi >> 8;
    const int pix0 = (bi & 255) << 6;
    const int lane = tid & 63, wv = tid >> 6;
    const int l15  = lane & 15, quad = lane >> 4;
    const int pl   = wv * 4 + quad;                 // this thread's pair slot per chunk

    // weights chunk k -> wl[s] via global_load_lds (linear dest, 4 rows/instr)
    auto stage_w = [&](int k, int s) {
        const U16* src = wfb + (size_t)(wv * 128 + quad) * 512 + k * 32 + l15 * 2;
        U16* dst = &wl[s][wv * 128 * 32];
#pragma unroll
        for (int j = 0; j < 32; ++j)
            gl_lds4(src + (size_t)j * 4 * 512, dst + j * 4 * 32);
    };
    // input chunk k: issue loads (early) / pack+write (late)
    auto in_load = [&](int k, f32x4& v0, f32x4& v1, float& a0, float& a1) {
        const int c = k * 32 + pl * 2;
        a0 = att[b * 512 + c];
        a1 = att[b * 512 + c + 1];
        const f32x4* e4 = (const f32x4*)(ef + (size_t)(b * 512 + c) * 16384 + pix0) + l15;
        v0 = e4[0];
        v1 = e4[4096];
    };
    auto in_write = [&](int s, const f32x4& v0, const f32x4& v1, float a0, float a1) {
#pragma unroll
        for (int i = 0; i < 4; ++i)
            kb[s][(l15 * 4 + i) * KP + pl] =
                (U32)f2bf(v0[i] * a0) | ((U32)f2bf(v1[i] * a1) << 16);
    };

    f32x4 acc[4][8];
#pragma unroll
    for (int i = 0; i < 4; ++i)
#pragma unroll
        for (int j = 0; j < 8; ++j) {
            f32x4 z = {0.f, 0.f, 0.f, 0.f};
            acc[i][j] = z;
        }

    {
        f32x4 v0, v1; float a0, a1;
        in_load(0, v0, v1, a0, a1);
        in_write(0, v0, v1, a0, a1);
        stage_w(0, 0);
    }
    __syncthreads();

#pragma unroll 1
    for (int k = 0; k < 16; ++k) {
        const int cur = k & 1;
        f32x4 v0n, v1n; float a0n, a1n;
        if (k < 15) {
            stage_w(k + 1, cur ^ 1);           // gll prefetch (no result regs)
            in_load(k + 1, v0n, v1n, a0n, a1n); // loads in flight across GEMM
        }
        // ---- GEMM chunk k: pure LDS + MFMA ----
        bf16x8 a[4];
#pragma unroll
        for (int mt = 0; mt < 4; ++mt)
            a[mt] = *(const bf16x8*)&kb[cur][(mt * 16 + l15) * KP + quad * 4];
#pragma unroll
        for (int nt = 0; nt < 8; ++nt) {
            bf16x8 bw = *(const bf16x8*)&wl[cur][(wv * 128 + nt * 16 + l15) * 32 + quad * 8];
#pragma unroll
            for (int mt = 0; mt < 4; ++mt)
                acc[mt][nt] = __builtin_amdgcn_mfma_f32_16x16x32_bf16(a[mt], bw, acc[mt][nt], 0, 0, 0);
        }
        if (k < 15) in_write(cur ^ 1, v0n, v1n, a0n, a1n);
        __syncthreads();
    }

    // ---- bias then LN stats (sum, sumsq over all 512 channels per pixel) ----
#pragma unroll
    for (int nt = 0; nt < 8; ++nt) {
        const float bz = bfu[wv * 128 + nt * 16 + l15];
#pragma unroll
        for (int mt = 0; mt < 4; ++mt)
#pragma unroll
            for (int r = 0; r < 4; ++r)
                acc[mt][nt][r] += bz;
    }
#pragma unroll
    for (int mt = 0; mt < 4; ++mt)
#pragma unroll
        for (int r = 0; r < 4; ++r) {
            float s = 0.f, q = 0.f;
#pragma unroll
            for (int nt = 0; nt < 8; ++nt) {
                float v = acc[mt][nt][r];
                s += v; q += v * v;
            }
#pragma unroll
            for (int off = 1; off < 16; off <<= 1) {
                s += __shfl_xor(s, off, 64);
                q += __shfl_xor(q, off, 64);
            }
            if (l15 == 0) {
                const int p = mt * 16 + quad * 4 + r;
                red_s[p * 4 + wv] = s;
                red_q[p * 4 + wv] = q;
            }
        }
    __syncthreads();
    if (tid < 64) {
        float S = red_s[tid * 4] + red_s[tid * 4 + 1] + red_s[tid * 4 + 2] + red_s[tid * 4 + 3];
        float Q = red_q[tid * 4] + red_q[tid * 4 + 1] + red_q[tid * 4 + 2] + red_q[tid * 4 + 3];
        float mu  = S * (1.0f / 512.0f);
        float var = fmaxf(Q * (1.0f / 512.0f) - mu * mu, 0.0f);
        mu_s[tid] = mu;
        iv_s[tid] = rsqrtf(var + 1e-6f);
    }
    __syncthreads();
    // ---- epilogue: LN + GELU + residual, direct float4 stores from acc ----
#pragma unroll
    for (int nt = 0; nt < 8; ++nt) {
        const int o = wv * 128 + nt * 16 + l15;
        const float g  = lng[o];
        const float be = lnb[o];
        const size_t rowoff = (size_t)(b * 512 + o) * 16384 + pix0;
#pragma unroll
        for (int mt = 0; mt < 4; ++mt) {
            const int pb = mt * 16 + quad * 4;
            f32x4 xv = *(const f32x4*)&x[rowoff + pb];
            f32x4 ov;
#pragma unroll
            for (int r = 0; r < 4; ++r) {
                const int p = pb + r;
                float z = (acc[mt][nt][r] - mu_s[p]) * iv_s[p];
                float y = z * g + be;
                ov[r] = gelu_f(y) + xv[r];
            }
            *(f32x4*)&out[rowoff + pb] = ov;
        }
    }
}

extern "C" void kernel_launch(void* const* d_in, const int* in_sizes, int n_in,
                              void* d_out, int out_size, void* d_ws, size_t ws_size,
                              hipStream_t stream)
{
    const float* x   = (const float*)d_in[0];
    const float* wB  = (const float*)d_in[1];
    const float* bB  = (const float*)d_in[2];
    const float* bg  = (const float*)d_in[3];
    const float* bbt = (const float*)d_in[4];
    const float* w1  = (const float*)d_in[5];
    const float* b1  = (const float*)d_in[6];
    const float* w2  = (const float*)d_in[7];
    const float* b2  = (const float*)d_in[8];
    const float* wf  = (const float*)d_in[9];
    const float* bfu = (const float*)d_in[10];
    const float* lng = (const float*)d_in[11];
    const float* lnb = (const float*)d_in[12];
    float* out = (float*)d_out;

    // d_ws: pooled 8K | att 8K | zero-page 4K | wBb 512K | wfb 512K | ef 128M (if fits)
    float* pooled = (float*)d_ws;
    float* att    = (float*)((char*)d_ws + 8192);
    float* zb     = (float*)((char*)d_ws + 16384);
    U16*   wBb    = (U16*)((char*)d_ws + 20480);
    U16*   wfb    = (U16*)((char*)d_ws + 20480 + 524288);
    const size_t EF_OFF  = 20480 + 2 * 524288;              // 1069056 (16B-aligned)
    const size_t EF_SIZE = (size_t)4 * 512 * 16384 * 4;     // 134217728
    float* ef = (ws_size >= EF_OFF + EF_SIZE) ? (float*)((char*)d_ws + EF_OFF) : out;

    hipMemsetAsync(pooled, 0, 2048 * sizeof(float), stream);
    hipMemsetAsync(zb, 0, 4096, stream);
    hipLaunchKernelGGL(k0_cvt, dim3(1024), dim3(256), 0, stream, wB, wf, wBb, wfb);
    hipLaunchKernelGGL(k1_branch, dim3(1024), dim3(256), 0, stream,
                       x, wBb, bB, bg, bbt, zb, ef, pooled);
    hipLaunchKernelGGL(k2_att, dim3(1), dim3(256), 0, stream,
                       pooled, w1, b1, w2, b2, att);
    hipLaunchKernelGGL(k3_fuse, dim3(1024), dim3(256), 0, stream,
                       ef, att, wfb, bfu, lng, lnb, x, out);
}